// Round 6
// baseline (203.978 us; speedup 1.0000x reference)
//
#include <hip/hip_runtime.h>

#define H 256
#define NB 2048
#define BATCH 8
#define NSPLIT 8
#define KSPAN (NB / NSPLIT)   // 256 keys per split
#define NCHUNK (KSPAN / 16)   // 16 chunks of 16 keys

typedef unsigned short u16;
using bf16x8 = __attribute__((ext_vector_type(8))) __bf16;
using f32x4  = __attribute__((ext_vector_type(4))) float;

typedef const __attribute__((address_space(1))) void gv_t;
typedef __attribute__((address_space(3))) void lv_t;

// async 16B-per-lane global->LDS: lds dst is wave-uniform base, lane i lands at base+16*i
__device__ __forceinline__ void gl_lds16(const void* g, void* l) {
    __builtin_amdgcn_global_load_lds((gv_t*)g, (lv_t*)l, 16, 0, 0);
}

#define MFMA(a, b, c) __builtin_amdgcn_mfma_f32_16x16x32_bf16(a, b, c, 0, 0, 0)

__device__ __forceinline__ u16 f2bf(float f) {
    union { float f; unsigned u; } v; v.f = f;
    unsigned r = v.u + 0x7fffu + ((v.u >> 16) & 1u);  // RNE
    return (u16)(r >> 16);
}

// ---- coalesced weight prep (one block per row f):
//   wqb/wkb = bf16(Wq/Wk) row-major; wvw[f] = Wv[f,:]·Ww; kbv[f] = Wk[f,:]·bq ----
__global__ __launch_bounds__(256) void wprep_kernel(
        const float* __restrict__ Wq, const float* __restrict__ Wk,
        const float* __restrict__ Wv, const float* __restrict__ Ww,
        const float* __restrict__ bq,
        u16* __restrict__ wqb, u16* __restrict__ wkb,
        float* __restrict__ wvw, float* __restrict__ kbv) {
    int f = blockIdx.x, t = threadIdx.x;
    float wq = Wq[f * H + t];
    wqb[f * H + t] = f2bf(wq);
    float wk = Wk[f * H + t];
    wkb[f * H + t] = f2bf(wk);
    float p = Wv[f * H + t] * Ww[t];
    float r = wk * bq[t];
    for (int o = 32; o; o >>= 1) { p += __shfl_xor(p, o); r += __shfl_xor(r, o); }
    __shared__ float redp[4], redr[4];
    int w = t >> 6, lane = t & 63;
    if (lane == 0) { redp[w] = p; redr[w] = r; }
    __syncthreads();
    if (t == 0) {
        wvw[f] = redp[0] + redp[1] + redp[2] + redp[3];
        kbv[f] = redr[0] + redr[1] + redr[2] + redr[3];
    }
}

// ---- x -> bf16; per-row: u = x·wvw + bv·Ww, d = (x·kbv)/16, e = exp(d);
//      store uee[row] = {e*u, e}.  One wave per row. ----
__global__ __launch_bounds__(256) void cvtu_kernel(
        const float* __restrict__ x, const float* __restrict__ wvw,
        const float* __restrict__ kbv, const float* __restrict__ bv,
        const float* __restrict__ Ww,
        u16* __restrict__ xbf, float2* __restrict__ uee) {
    int lane = threadIdx.x & 63;
    int row  = blockIdx.x * 4 + (threadIdx.x >> 6);
    float4 xv = *(const float4*)(x + row * H + lane * 4);
    ushort4 o;
    o.x = f2bf(xv.x); o.y = f2bf(xv.y); o.z = f2bf(xv.z); o.w = f2bf(xv.w);
    *(ushort4*)(xbf + row * H + lane * 4) = o;
    float4 wv = *(const float4*)(wvw + lane * 4);
    float s = xv.x * wv.x + xv.y * wv.y + xv.z * wv.z + xv.w * wv.w;
    float4 kv = *(const float4*)(kbv + lane * 4);
    float d = xv.x * kv.x + xv.y * kv.y + xv.z * kv.z + xv.w * kv.w;
    float4 bvv = *(const float4*)(bv + lane * 4);
    float4 www = *(const float4*)(Ww + lane * 4);
    float c = bvv.x * www.x + bvv.y * www.y + bvv.z * www.z + bvv.w * www.w;
    for (int o2 = 32; o2; o2 >>= 1) {
        s += __shfl_xor(s, o2); d += __shfl_xor(d, o2); c += __shfl_xor(c, o2);
    }
    if (lane == 0) {
        float e = __expf(d * 0.0625f);
        uee[row] = make_float2(e * (s + c), e);
    }
}

// ---- generic C = (A @ B^T) * scale, bf16 in/out, MFMA 16x16x32, M=2/wave. ----
__global__ __launch_bounds__(256) void gemm_bt_kernel(
        const u16* __restrict__ A, const u16* __restrict__ B,
        u16* __restrict__ C, float scale) {
    __shared__ u16 bt[16384];   // 32KB fragment-major
    int tid = threadIdx.x;
    int mb = blockIdx.x * 128, nb = blockIdx.y * 64;
    int w = tid >> 6, lane = tid & 63;
    int l15 = lane & 15, quad = lane >> 4;

    {   // wave w stages t=w, ks=0..7
        const u16* gsrc = B + (nb + w * 16 + l15) * H + quad * 8;
        for (int ks = 0; ks < 8; ++ks)
            gl_lds16(gsrc + ks * 32, bt + (w * 8 + ks) * 512);
    }

    bf16x8 a[2][8];
    for (int mi = 0; mi < 2; ++mi) {
        const u16* abase = A + (size_t)(mb + w * 32 + mi * 16 + l15) * H + quad * 8;
        for (int ks = 0; ks < 8; ++ks) a[mi][ks] = *(const bf16x8*)(abase + ks * 32);
    }
    __syncthreads();

    f32x4 acc[2][4] = {};
    for (int ks = 0; ks < 8; ++ks)
        for (int t = 0; t < 4; ++t) {
            bf16x8 b = *(const bf16x8*)(bt + ((t * 8 + ks) * 64 + lane) * 8);
            acc[0][t] = MFMA(a[0][ks], b, acc[0][t]);
            acc[1][t] = MFMA(a[1][ks], b, acc[1][t]);
        }

    for (int mi = 0; mi < 2; ++mi) {
        int m = mb + w * 32 + mi * 16 + quad * 4;
        for (int t = 0; t < 4; ++t) {
            int n = nb + t * 16 + l15;
            for (int r = 0; r < 4; ++r)
                C[(size_t)(m + r) * H + n] = f2bf(acc[mi][t][r] * scale);
        }
    }
}

// ---- attention, single-wave workgroups, NO LDS, NO barriers.
//      Each 64-thread block = 1 wave: 32 q-rows (aq resident, 64 VGPR) x one
//      K-split. B-fragments (keys) load global->register with a 2-deep
//      register double-buffer; the wave self-paces on fine-grained vmcnt —
//      no s_barrier drain anywhere. Grid 1D with batch in the low 3 bits so
//      round-robin dispatch pins batch b to XCD b (x-slice+T-slice fit 4MB L2). ----
__global__ __launch_bounds__(64, 3) void attn_kernel(
        const u16* __restrict__ T, const u16* __restrict__ xbf,
        const float2* __restrict__ uee,
        float* __restrict__ pnum, float* __restrict__ pden) {
    int id = blockIdx.x;
    int b = id & 7, rest = id >> 3;
    int qc = rest & 63, sp = rest >> 6;
    int lane = threadIdx.x;
    int l15 = lane & 15, quad = lane >> 4;

    // resident A fragments: 32 q-rows
    bf16x8 aq[2][8];
    {
        const u16* qbase = T + (size_t)(b * NB + qc * 32 + l15) * H + quad * 8;
        #pragma unroll
        for (int mi = 0; mi < 2; ++mi)
            #pragma unroll
            for (int ks = 0; ks < 8; ++ks)
                aq[mi][ks] = *(const bf16x8*)(qbase + mi * 16 * H + ks * 32);
    }

    const u16* xb = xbf + ((size_t)b * NB + sp * KSPAN) * H;
    const float2* uep = uee + (size_t)b * NB + sp * KSPAN;

    bf16x8 bfr[2][8];
    float2 uv[2];
    {
        const u16* krow = xb + (size_t)l15 * H + quad * 8;
        #pragma unroll
        for (int ks = 0; ks < 8; ++ks) bfr[0][ks] = *(const bf16x8*)(krow + ks * 32);
        uv[0] = uep[l15];
    }

    float ls[2][4] = {}, as_[2][4] = {};

    #pragma unroll
    for (int ch = 0; ch < NCHUNK; ++ch) {
        int cur = ch & 1;
        if (ch + 1 < NCHUNK) {   // prefetch next chunk into the other buffer
            const u16* nrow = xb + (size_t)((ch + 1) * 16 + l15) * H + quad * 8;
            #pragma unroll
            for (int ks = 0; ks < 8; ++ks)
                bfr[cur ^ 1][ks] = *(const bf16x8*)(nrow + ks * 32);
            uv[cur ^ 1] = uep[(ch + 1) * 16 + l15];
        }
        f32x4 acc[2] = {};
        #pragma unroll
        for (int ks = 0; ks < 8; ++ks) {
            acc[0] = MFMA(aq[0][ks], bfr[cur][ks], acc[0]);
            acc[1] = MFMA(aq[1][ks], bfr[cur][ks], acc[1]);
        }
        float uex = uv[cur].x, uey = uv[cur].y;
        #pragma unroll
        for (int mi = 0; mi < 2; ++mi)
            #pragma unroll
            for (int r = 0; r < 4; ++r) {
                float p = __expf(acc[mi][r]);
                as_[mi][r] += p * uex;
                ls[mi][r]  += p * uey;
            }
    }

    // reduce over the 16 key-columns (l15)
    #pragma unroll
    for (int mi = 0; mi < 2; ++mi)
        #pragma unroll
        for (int r = 0; r < 4; ++r)
            for (int o = 1; o < 16; o <<= 1) {
                ls[mi][r]  += __shfl_xor(ls[mi][r], o);
                as_[mi][r] += __shfl_xor(as_[mi][r], o);
            }

    if (l15 == 0) {
        size_t base = (size_t)(sp * BATCH + b) * NB + qc * 32 + quad * 4;
        #pragma unroll
        for (int mi = 0; mi < 2; ++mi)
            #pragma unroll
            for (int r = 0; r < 4; ++r) {
                pnum[base + mi * 16 + r] = as_[mi][r];
                pden[base + mi * 16 + r] = ls[mi][r];
            }
    }
}

// ---- combine K-splits: out = sum(num)/sum(den) + bw ----
__global__ __launch_bounds__(256) void finalize_kernel(
        const float* __restrict__ pnum, const float* __restrict__ pden,
        const float* __restrict__ bw, float* __restrict__ out) {
    int i = blockIdx.x * 256 + threadIdx.x;   // i = b*NB + n
    float num = 0.f, den = 0.f;
    for (int sp = 0; sp < NSPLIT; ++sp) {
        num += pnum[sp * (BATCH * NB) + i];
        den += pden[sp * (BATCH * NB) + i];
    }
    out[i] = num / den + bw[0];
}

extern "C" void kernel_launch(void* const* d_in, const int* in_sizes, int n_in,
                              void* d_out, int out_size, void* d_ws, size_t ws_size,
                              hipStream_t stream) {
    (void)in_sizes; (void)n_in; (void)out_size; (void)ws_size;
    const float* x  = (const float*)d_in[0];
    const float* Wq = (const float*)d_in[1];
    const float* bq = (const float*)d_in[2];
    const float* Wk = (const float*)d_in[3];
    const float* bk = (const float*)d_in[4];  (void)bk;  // cancels in softmax
    const float* Wv = (const float*)d_in[5];
    const float* bv = (const float*)d_in[6];
    const float* Ww = (const float*)d_in[7];
    const float* bw = (const float*)d_in[8];
    float* out = (float*)d_out;

    u16* xbf = (u16*)d_ws;                     // 4194304 u16 (8 MB)
    u16* Tbf = xbf + 4194304;                  // 4194304 u16 (8 MB)
    u16* aTb = Tbf + 4194304;                  // 65536 u16
    u16* wqb = aTb + 65536;                    // 65536 u16
    u16* wkb = wqb + 65536;                    // 65536 u16
    float* wvw = (float*)(wkb + 65536);        // 256 f32
    float* kbv = wvw + 256;                    // 256 f32
    float2* uee = (float2*)(kbv + 256);        // 16384 float2
    float* pnum = (float*)(uee + 16384);       // NSPLIT*16384 f32
    float* pden = pnum + NSPLIT * BATCH * NB;  // NSPLIT*16384 f32

    hipLaunchKernelGGL(wprep_kernel, dim3(256), dim3(256), 0, stream,
                       Wq, Wk, Wv, Ww, bq, wqb, wkb, wvw, kbv);
    // aT[f][e] = (Wk[f,:]·Wq[e,:])/16
    hipLaunchKernelGGL(gemm_bt_kernel, dim3(2, 4), dim3(256), 0, stream,
                       wkb, wqb, aTb, 0.0625f);
    hipLaunchKernelGGL(cvtu_kernel, dim3(4096), dim3(256), 0, stream,
                       x, wvw, kbv, bv, Ww, xbf, uee);
    // T = xbf @ aT^T (aTb rows are B-operand rows)
    hipLaunchKernelGGL(gemm_bt_kernel, dim3(128, 4), dim3(256), 0, stream,
                       xbf, aTb, Tbf, 1.0f);
    hipLaunchKernelGGL(attn_kernel, dim3(64 * BATCH * NSPLIT), dim3(64), 0, stream,
                       Tbf, xbf, uee, pnum, pden);
    hipLaunchKernelGGL(finalize_kernel, dim3(64), dim3(256), 0, stream,
                       pnum, pden, bw, out);
}

// Round 7
// 177.369 us; speedup vs baseline: 1.1500x; 1.1500x over previous
//
#include <hip/hip_runtime.h>

#define H 256
#define NB 2048
#define BATCH 8
#define NSPLIT 8
#define KSPAN (NB / NSPLIT)   // 256 keys per split
#define NCHUNK (KSPAN / 16)   // 16 chunks of 16 keys

typedef unsigned short u16;
using bf16x8 = __attribute__((ext_vector_type(8))) __bf16;
using f32x4  = __attribute__((ext_vector_type(4))) float;

typedef const __attribute__((address_space(1))) void gv_t;
typedef __attribute__((address_space(3))) void lv_t;

// async 16B-per-lane global->LDS: lds dst is wave-uniform base, lane i lands at base+16*i
__device__ __forceinline__ void gl_lds16(const void* g, void* l) {
    __builtin_amdgcn_global_load_lds((gv_t*)g, (lv_t*)l, 16, 0, 0);
}

#define MFMA(a, b, c) __builtin_amdgcn_mfma_f32_16x16x32_bf16(a, b, c, 0, 0, 0)

__device__ __forceinline__ u16 f2bf(float f) {
    union { float f; unsigned u; } v; v.f = f;
    unsigned r = v.u + 0x7fffu + ((v.u >> 16) & 1u);  // RNE
    return (u16)(r >> 16);
}

// ---- coalesced weight prep (one block per row f):
//   wqb/wkb = bf16(Wq/Wk) row-major; wvw[f] = Wv[f,:]·Ww; kbv[f] = Wk[f,:]·bq ----
__global__ __launch_bounds__(256) void wprep_kernel(
        const float* __restrict__ Wq, const float* __restrict__ Wk,
        const float* __restrict__ Wv, const float* __restrict__ Ww,
        const float* __restrict__ bq,
        u16* __restrict__ wqb, u16* __restrict__ wkb,
        float* __restrict__ wvw, float* __restrict__ kbv) {
    int f = blockIdx.x, t = threadIdx.x;
    float wq = Wq[f * H + t];
    wqb[f * H + t] = f2bf(wq);
    float wk = Wk[f * H + t];
    wkb[f * H + t] = f2bf(wk);
    float p = Wv[f * H + t] * Ww[t];
    float r = wk * bq[t];
    for (int o = 32; o; o >>= 1) { p += __shfl_xor(p, o); r += __shfl_xor(r, o); }
    __shared__ float redp[4], redr[4];
    int w = t >> 6, lane = t & 63;
    if (lane == 0) { redp[w] = p; redr[w] = r; }
    __syncthreads();
    if (t == 0) {
        wvw[f] = redp[0] + redp[1] + redp[2] + redp[3];
        kbv[f] = redr[0] + redr[1] + redr[2] + redr[3];
    }
}

// ---- x -> bf16; per-row: u = x·wvw + bv·Ww, d = (x·kbv)/16, e = exp(d);
//      store uee[row] = {e*u, e}.  One wave per row. ----
__global__ __launch_bounds__(256) void cvtu_kernel(
        const float* __restrict__ x, const float* __restrict__ wvw,
        const float* __restrict__ kbv, const float* __restrict__ bv,
        const float* __restrict__ Ww,
        u16* __restrict__ xbf, float2* __restrict__ uee) {
    int lane = threadIdx.x & 63;
    int row  = blockIdx.x * 4 + (threadIdx.x >> 6);
    float4 xv = *(const float4*)(x + row * H + lane * 4);
    ushort4 o;
    o.x = f2bf(xv.x); o.y = f2bf(xv.y); o.z = f2bf(xv.z); o.w = f2bf(xv.w);
    *(ushort4*)(xbf + row * H + lane * 4) = o;
    float4 wv = *(const float4*)(wvw + lane * 4);
    float s = xv.x * wv.x + xv.y * wv.y + xv.z * wv.z + xv.w * wv.w;
    float4 kv = *(const float4*)(kbv + lane * 4);
    float d = xv.x * kv.x + xv.y * kv.y + xv.z * kv.z + xv.w * kv.w;
    float4 bvv = *(const float4*)(bv + lane * 4);
    float4 www = *(const float4*)(Ww + lane * 4);
    float c = bvv.x * www.x + bvv.y * www.y + bvv.z * www.z + bvv.w * www.w;
    for (int o2 = 32; o2; o2 >>= 1) {
        s += __shfl_xor(s, o2); d += __shfl_xor(d, o2); c += __shfl_xor(c, o2);
    }
    if (lane == 0) {
        float e = __expf(d * 0.0625f);
        uee[row] = make_float2(e * (s + c), e);
    }
}

// ---- generic C = (A @ B^T) * scale, bf16 in/out, MFMA 16x16x32, M=2/wave. ----
__global__ __launch_bounds__(256) void gemm_bt_kernel(
        const u16* __restrict__ A, const u16* __restrict__ B,
        u16* __restrict__ C, float scale) {
    __shared__ u16 bt[16384];   // 32KB fragment-major
    int tid = threadIdx.x;
    int mb = blockIdx.x * 128, nb = blockIdx.y * 64;
    int w = tid >> 6, lane = tid & 63;
    int l15 = lane & 15, quad = lane >> 4;

    {   // wave w stages t=w, ks=0..7
        const u16* gsrc = B + (nb + w * 16 + l15) * H + quad * 8;
        for (int ks = 0; ks < 8; ++ks)
            gl_lds16(gsrc + ks * 32, bt + (w * 8 + ks) * 512);
    }

    bf16x8 a[2][8];
    for (int mi = 0; mi < 2; ++mi) {
        const u16* abase = A + (size_t)(mb + w * 32 + mi * 16 + l15) * H + quad * 8;
        for (int ks = 0; ks < 8; ++ks) a[mi][ks] = *(const bf16x8*)(abase + ks * 32);
    }
    __syncthreads();

    f32x4 acc[2][4] = {};
    for (int ks = 0; ks < 8; ++ks)
        for (int t = 0; t < 4; ++t) {
            bf16x8 b = *(const bf16x8*)(bt + ((t * 8 + ks) * 64 + lane) * 8);
            acc[0][t] = MFMA(a[0][ks], b, acc[0][t]);
            acc[1][t] = MFMA(a[1][ks], b, acc[1][t]);
        }

    for (int mi = 0; mi < 2; ++mi) {
        int m = mb + w * 32 + mi * 16 + quad * 4;
        for (int t = 0; t < 4; ++t) {
            int n = nb + t * 16 + l15;
            for (int r = 0; r < 4; ++r)
                C[(size_t)(m + r) * H + n] = f2bf(acc[mi][t][r] * scale);
        }
    }
}

// ---- attention, single-wave workgroups, NO LDS, NO barriers.
//      Each 64-thread block = 1 wave: 32 q-rows (aq resident, 64 VGPR) x one
//      K-split. Key fragments load global->register with a 3-deep register
//      pipeline (prefetch distance 2 covers L2 latency); the wave self-paces
//      on fine-grained vmcnt — no s_barrier drain anywhere. Batch in the low
//      3 bits of blockIdx pins batch b to XCD b (x+T slices fit 4MB L2).
//      __launch_bounds__(64,2): 256-VGPR cap, need ~205 — NO SPILL (R6's
//      (64,3) capped at ~170 and spilled 93MB to scratch). ----
__global__ __launch_bounds__(64, 2) void attn_kernel(
        const u16* __restrict__ T, const u16* __restrict__ xbf,
        const float2* __restrict__ uee,
        float* __restrict__ pnum, float* __restrict__ pden) {
    int id = blockIdx.x;
    int b = id & 7, rest = id >> 3;
    int qc = rest & 63, sp = rest >> 6;
    int lane = threadIdx.x;
    int l15 = lane & 15, quad = lane >> 4;

    // resident A fragments: 32 q-rows
    bf16x8 aq[2][8];
    {
        const u16* qbase = T + (size_t)(b * NB + qc * 32 + l15) * H + quad * 8;
        #pragma unroll
        for (int mi = 0; mi < 2; ++mi)
            #pragma unroll
            for (int ks = 0; ks < 8; ++ks)
                aq[mi][ks] = *(const bf16x8*)(qbase + mi * 16 * H + ks * 32);
    }

    const u16* xb = xbf + ((size_t)b * NB + sp * KSPAN) * H;
    const float2* uep = uee + (size_t)b * NB + sp * KSPAN;

    bf16x8 bfr[3][8];
    float2 uv[3];
    #pragma unroll
    for (int pf = 0; pf < 2; ++pf) {
        const u16* krow = xb + (size_t)(pf * 16 + l15) * H + quad * 8;
        #pragma unroll
        for (int ks = 0; ks < 8; ++ks) bfr[pf][ks] = *(const bf16x8*)(krow + ks * 32);
        uv[pf] = uep[pf * 16 + l15];
    }

    float ls[2][4] = {}, as_[2][4] = {};

    #pragma unroll
    for (int ch = 0; ch < NCHUNK; ++ch) {
        int cur = ch % 3;
        if (ch + 2 < NCHUNK) {   // prefetch chunk ch+2 into the free buffer
            int nxt = (ch + 2) % 3;
            const u16* nrow = xb + (size_t)((ch + 2) * 16 + l15) * H + quad * 8;
            #pragma unroll
            for (int ks = 0; ks < 8; ++ks)
                bfr[nxt][ks] = *(const bf16x8*)(nrow + ks * 32);
            uv[nxt] = uep[(ch + 2) * 16 + l15];
        }
        f32x4 acc[2] = {};
        #pragma unroll
        for (int ks = 0; ks < 8; ++ks) {
            acc[0] = MFMA(aq[0][ks], bfr[cur][ks], acc[0]);
            acc[1] = MFMA(aq[1][ks], bfr[cur][ks], acc[1]);
        }
        float uex = uv[cur].x, uey = uv[cur].y;
        #pragma unroll
        for (int mi = 0; mi < 2; ++mi)
            #pragma unroll
            for (int r = 0; r < 4; ++r) {
                float p = __expf(acc[mi][r]);
                as_[mi][r] += p * uex;
                ls[mi][r]  += p * uey;
            }
    }

    // reduce over the 16 key-columns (l15)
    #pragma unroll
    for (int mi = 0; mi < 2; ++mi)
        #pragma unroll
        for (int r = 0; r < 4; ++r)
            for (int o = 1; o < 16; o <<= 1) {
                ls[mi][r]  += __shfl_xor(ls[mi][r], o);
                as_[mi][r] += __shfl_xor(as_[mi][r], o);
            }

    if (l15 == 0) {
        size_t base = (size_t)(sp * BATCH + b) * NB + qc * 32 + quad * 4;
        #pragma unroll
        for (int mi = 0; mi < 2; ++mi)
            #pragma unroll
            for (int r = 0; r < 4; ++r) {
                pnum[base + mi * 16 + r] = as_[mi][r];
                pden[base + mi * 16 + r] = ls[mi][r];
            }
    }
}

// ---- combine K-splits: out = sum(num)/sum(den) + bw ----
__global__ __launch_bounds__(256) void finalize_kernel(
        const float* __restrict__ pnum, const float* __restrict__ pden,
        const float* __restrict__ bw, float* __restrict__ out) {
    int i = blockIdx.x * 256 + threadIdx.x;   // i = b*NB + n
    float num = 0.f, den = 0.f;
    for (int sp = 0; sp < NSPLIT; ++sp) {
        num += pnum[sp * (BATCH * NB) + i];
        den += pden[sp * (BATCH * NB) + i];
    }
    out[i] = num / den + bw[0];
}

extern "C" void kernel_launch(void* const* d_in, const int* in_sizes, int n_in,
                              void* d_out, int out_size, void* d_ws, size_t ws_size,
                              hipStream_t stream) {
    (void)in_sizes; (void)n_in; (void)out_size; (void)ws_size;
    const float* x  = (const float*)d_in[0];
    const float* Wq = (const float*)d_in[1];
    const float* bq = (const float*)d_in[2];
    const float* Wk = (const float*)d_in[3];
    const float* bk = (const float*)d_in[4];  (void)bk;  // cancels in softmax
    const float* Wv = (const float*)d_in[5];
    const float* bv = (const float*)d_in[6];
    const float* Ww = (const float*)d_in[7];
    const float* bw = (const float*)d_in[8];
    float* out = (float*)d_out;

    u16* xbf = (u16*)d_ws;                     // 4194304 u16 (8 MB)
    u16* Tbf = xbf + 4194304;                  // 4194304 u16 (8 MB)
    u16* aTb = Tbf + 4194304;                  // 65536 u16
    u16* wqb = aTb + 65536;                    // 65536 u16
    u16* wkb = wqb + 65536;                    // 65536 u16
    float* wvw = (float*)(wkb + 65536);        // 256 f32
    float* kbv = wvw + 256;                    // 256 f32
    float2* uee = (float2*)(kbv + 256);        // 16384 float2
    float* pnum = (float*)(uee + 16384);       // NSPLIT*16384 f32
    float* pden = pnum + NSPLIT * BATCH * NB;  // NSPLIT*16384 f32

    hipLaunchKernelGGL(wprep_kernel, dim3(256), dim3(256), 0, stream,
                       Wq, Wk, Wv, Ww, bq, wqb, wkb, wvw, kbv);
    // aT[f][e] = (Wk[f,:]·Wq[e,:])/16
    hipLaunchKernelGGL(gemm_bt_kernel, dim3(2, 4), dim3(256), 0, stream,
                       wkb, wqb, aTb, 0.0625f);
    hipLaunchKernelGGL(cvtu_kernel, dim3(4096), dim3(256), 0, stream,
                       x, wvw, kbv, bv, Ww, xbf, uee);
    // T = xbf @ aT^T (aTb rows are B-operand rows)
    hipLaunchKernelGGL(gemm_bt_kernel, dim3(128, 4), dim3(256), 0, stream,
                       xbf, aTb, Tbf, 1.0f);
    hipLaunchKernelGGL(attn_kernel, dim3(64 * BATCH * NSPLIT), dim3(64), 0, stream,
                       Tbf, xbf, uee, pnum, pden);
    hipLaunchKernelGGL(finalize_kernel, dim3(64), dim3(256), 0, stream,
                       pnum, pden, bw, out);
}

// Round 8
// 126.443 us; speedup vs baseline: 1.6132x; 1.4028x over previous
//
#include <hip/hip_runtime.h>

#define H 256
#define NB 2048
#define BATCH 8
#define NSPLIT 8
#define KSPAN (NB / NSPLIT)   // 256 keys per split
#define NHALF (KSPAN / 32)    // 8 half-tiles of 32 keys

typedef unsigned short u16;
using bf16x8 = __attribute__((ext_vector_type(8))) __bf16;
using f32x4  = __attribute__((ext_vector_type(4))) float;

typedef const __attribute__((address_space(1))) void gv_t;
typedef __attribute__((address_space(3))) void lv_t;

// async 16B-per-lane global->LDS: lds dst is wave-uniform base, lane i lands at base+16*i
__device__ __forceinline__ void gl_lds16(const void* g, void* l) {
    __builtin_amdgcn_global_load_lds((gv_t*)g, (lv_t*)l, 16, 0, 0);
}

#define MFMA(a, b, c) __builtin_amdgcn_mfma_f32_16x16x32_bf16(a, b, c, 0, 0, 0)

__device__ __forceinline__ u16 f2bf(float f) {
    union { float f; unsigned u; } v; v.f = f;
    unsigned r = v.u + 0x7fffu + ((v.u >> 16) & 1u);  // RNE
    return (u16)(r >> 16);
}

// ---- coalesced weight prep (one block per row f):
//   wqb/wkb = bf16(Wq/Wk) row-major; wvw[f] = Wv[f,:]·Ww; kbv[f] = Wk[f,:]·bq ----
__global__ __launch_bounds__(256) void wprep_kernel(
        const float* __restrict__ Wq, const float* __restrict__ Wk,
        const float* __restrict__ Wv, const float* __restrict__ Ww,
        const float* __restrict__ bq,
        u16* __restrict__ wqb, u16* __restrict__ wkb,
        float* __restrict__ wvw, float* __restrict__ kbv) {
    int f = blockIdx.x, t = threadIdx.x;
    float wq = Wq[f * H + t];
    wqb[f * H + t] = f2bf(wq);
    float wk = Wk[f * H + t];
    wkb[f * H + t] = f2bf(wk);
    float p = Wv[f * H + t] * Ww[t];
    float r = wk * bq[t];
    for (int o = 32; o; o >>= 1) { p += __shfl_xor(p, o); r += __shfl_xor(r, o); }
    __shared__ float redp[4], redr[4];
    int w = t >> 6, lane = t & 63;
    if (lane == 0) { redp[w] = p; redr[w] = r; }
    __syncthreads();
    if (t == 0) {
        wvw[f] = redp[0] + redp[1] + redp[2] + redp[3];
        kbv[f] = redr[0] + redr[1] + redr[2] + redr[3];
    }
}

// ---- x -> bf16; per-row: u = x·wvw + bv·Ww, d = (x·kbv)/16, e = exp(d);
//      store uee[row] = {e*u, e}.  One wave per row. ----
__global__ __launch_bounds__(256) void cvtu_kernel(
        const float* __restrict__ x, const float* __restrict__ wvw,
        const float* __restrict__ kbv, const float* __restrict__ bv,
        const float* __restrict__ Ww,
        u16* __restrict__ xbf, float2* __restrict__ uee) {
    int lane = threadIdx.x & 63;
    int row  = blockIdx.x * 4 + (threadIdx.x >> 6);
    float4 xv = *(const float4*)(x + row * H + lane * 4);
    ushort4 o;
    o.x = f2bf(xv.x); o.y = f2bf(xv.y); o.z = f2bf(xv.z); o.w = f2bf(xv.w);
    *(ushort4*)(xbf + row * H + lane * 4) = o;
    float4 wv = *(const float4*)(wvw + lane * 4);
    float s = xv.x * wv.x + xv.y * wv.y + xv.z * wv.z + xv.w * wv.w;
    float4 kv = *(const float4*)(kbv + lane * 4);
    float d = xv.x * kv.x + xv.y * kv.y + xv.z * kv.z + xv.w * kv.w;
    float4 bvv = *(const float4*)(bv + lane * 4);
    float4 www = *(const float4*)(Ww + lane * 4);
    float c = bvv.x * www.x + bvv.y * www.y + bvv.z * www.z + bvv.w * www.w;
    for (int o2 = 32; o2; o2 >>= 1) {
        s += __shfl_xor(s, o2); d += __shfl_xor(d, o2); c += __shfl_xor(c, o2);
    }
    if (lane == 0) {
        float e = __expf(d * 0.0625f);
        uee[row] = make_float2(e * (s + c), e);
    }
}

// ---- generic C = (A @ B^T) * scale, bf16 in/out, MFMA 16x16x32, M=2/wave. ----
__global__ __launch_bounds__(256) void gemm_bt_kernel(
        const u16* __restrict__ A, const u16* __restrict__ B,
        u16* __restrict__ C, float scale) {
    __shared__ u16 bt[16384];   // 32KB fragment-major
    int tid = threadIdx.x;
    int mb = blockIdx.x * 128, nb = blockIdx.y * 64;
    int w = tid >> 6, lane = tid & 63;
    int l15 = lane & 15, quad = lane >> 4;

    {   // wave w stages t=w, ks=0..7
        const u16* gsrc = B + (nb + w * 16 + l15) * H + quad * 8;
        for (int ks = 0; ks < 8; ++ks)
            gl_lds16(gsrc + ks * 32, bt + (w * 8 + ks) * 512);
    }

    bf16x8 a[2][8];
    for (int mi = 0; mi < 2; ++mi) {
        const u16* abase = A + (size_t)(mb + w * 32 + mi * 16 + l15) * H + quad * 8;
        for (int ks = 0; ks < 8; ++ks) a[mi][ks] = *(const bf16x8*)(abase + ks * 32);
    }
    __syncthreads();

    f32x4 acc[2][4] = {};
    for (int ks = 0; ks < 8; ++ks)
        for (int t = 0; t < 4; ++t) {
            bf16x8 b = *(const bf16x8*)(bt + ((t * 8 + ks) * 64 + lane) * 8);
            acc[0][t] = MFMA(a[0][ks], b, acc[0][t]);
            acc[1][t] = MFMA(a[1][ks], b, acc[1][t]);
        }

    for (int mi = 0; mi < 2; ++mi) {
        int m = mb + w * 32 + mi * 16 + quad * 4;
        for (int t = 0; t < 4; ++t) {
            int n = nb + t * 16 + l15;
            for (int r = 0; r < 4; ++r)
                C[(size_t)(m + r) * H + n] = f2bf(acc[mi][t][r] * scale);
        }
    }
}

// ---- attention: logit(n,m) = T[n]·x[m]; num += e^logit·(e·u)_m, den += e^logit·e_m.
//      M=4 subtiles/wave (64 q-rows), 256 q-rows/block: each ds_read_b128
//      B-fragment feeds 4 MFMAs -> LDS-pipe traffic halved vs M=2. All register
//      arrays indexed by UNROLLED CONSTANTS only (R6/R7: dynamic indices ->
//      alloca -> 21-93MB scratch traffic). 32-key halves, double-buffered LDS,
//      one barrier per half (async stage drains behind ~600cyc of compute).
//      Grid 512 = 2 blocks/CU resident; b in low 3 bits pins batch b -> XCD b. ----
__global__ __launch_bounds__(256, 2) void attn_kernel(
        const u16* __restrict__ T, const u16* __restrict__ xbf,
        const float2* __restrict__ uee,
        float* __restrict__ pnum, float* __restrict__ pden) {
    __shared__ u16 kt[16384];   // 2 x 16KB fragment-major half-tiles
    int tid = threadIdx.x;
    int id = blockIdx.x;
    int b = id & 7, rest = id >> 3;
    int qc = rest & 7, sp = rest >> 3;
    int w = tid >> 6, lane = tid & 63, l15 = lane & 15, quad = lane >> 4;
    int qb = qc * 256;

    // resident A fragments: 64 q-rows per wave (4 x 16)
    bf16x8 aq[4][8];
    {
        const u16* qbase = T + (size_t)(b * NB + qb + w * 64 + l15) * H + quad * 8;
        #pragma unroll
        for (int mi = 0; mi < 4; ++mi)
            #pragma unroll
            for (int ks = 0; ks < 8; ++ks)
                aq[mi][ks] = *(const bf16x8*)(qbase + mi * 16 * H + ks * 32);
    }

    const u16* xb = xbf + (size_t)b * NB * H;
    const float2* uep = uee + (size_t)b * NB;
    const int kb0 = sp * KSPAN;
    int c0 = w * 4;   // wave w stages chunks c0..c0+3 of the 16-chunk half

    // stage half 0
    #pragma unroll
    for (int j = 0; j < 4; ++j) {
        int c = c0 + j;
        gl_lds16(xb + (size_t)(kb0 + (c >> 3) * 16 + l15) * H + (c & 7) * 32 + quad * 8,
                 kt + c * 512);
    }
    __syncthreads();

    float ls[4][4] = {}, as_[4][4] = {};

    #pragma unroll 1
    for (int h = 0; h < NHALF; ++h) {
        const u16* ktc = kt + (h & 1) * 8192;
        if (h + 1 < NHALF) {   // stage next half into the other buffer
            int kb32 = kb0 + (h + 1) * 32;
            u16* dst = kt + ((h & 1) ^ 1) * 8192;
            #pragma unroll
            for (int j = 0; j < 4; ++j) {
                int c = c0 + j;
                gl_lds16(xb + (size_t)(kb32 + (c >> 3) * 16 + l15) * H + (c & 7) * 32 + quad * 8,
                         dst + c * 512);
            }
        }
        int kb32 = kb0 + h * 32;
        float2 uv0 = uep[kb32 + l15];
        float2 uv1 = uep[kb32 + 16 + l15];

        f32x4 acc[4][2] = {};
        #pragma unroll
        for (int ks = 0; ks < 8; ++ks)
            #pragma unroll
            for (int t = 0; t < 2; ++t) {
                bf16x8 bfr = *(const bf16x8*)(ktc + ((t * 8 + ks) * 64 + lane) * 8);
                acc[0][t] = MFMA(aq[0][ks], bfr, acc[0][t]);
                acc[1][t] = MFMA(aq[1][ks], bfr, acc[1][t]);
                acc[2][t] = MFMA(aq[2][ks], bfr, acc[2][t]);
                acc[3][t] = MFMA(aq[3][ks], bfr, acc[3][t]);
            }

        #pragma unroll
        for (int mi = 0; mi < 4; ++mi)
            #pragma unroll
            for (int r = 0; r < 4; ++r) {
                float p0 = __expf(acc[mi][0][r]);
                float p1 = __expf(acc[mi][1][r]);
                as_[mi][r] += p0 * uv0.x + p1 * uv1.x;
                ls[mi][r]  += p0 * uv0.y + p1 * uv1.y;
            }
        __syncthreads();
    }

    // reduce over the 16 key-columns (l15)
    #pragma unroll
    for (int mi = 0; mi < 4; ++mi)
        #pragma unroll
        for (int r = 0; r < 4; ++r)
            for (int o = 1; o < 16; o <<= 1) {
                ls[mi][r]  += __shfl_xor(ls[mi][r], o);
                as_[mi][r] += __shfl_xor(as_[mi][r], o);
            }

    if (l15 == 0) {
        size_t base = (size_t)(sp * BATCH + b) * NB + qb + w * 64 + quad * 4;
        #pragma unroll
        for (int mi = 0; mi < 4; ++mi)
            #pragma unroll
            for (int r = 0; r < 4; ++r) {
                pnum[base + mi * 16 + r] = as_[mi][r];
                pden[base + mi * 16 + r] = ls[mi][r];
            }
    }
}

// ---- combine K-splits: out = sum(num)/sum(den) + bw ----
__global__ __launch_bounds__(256) void finalize_kernel(
        const float* __restrict__ pnum, const float* __restrict__ pden,
        const float* __restrict__ bw, float* __restrict__ out) {
    int i = blockIdx.x * 256 + threadIdx.x;   // i = b*NB + n
    float num = 0.f, den = 0.f;
    for (int sp = 0; sp < NSPLIT; ++sp) {
        num += pnum[sp * (BATCH * NB) + i];
        den += pden[sp * (BATCH * NB) + i];
    }
    out[i] = num / den + bw[0];
}

extern "C" void kernel_launch(void* const* d_in, const int* in_sizes, int n_in,
                              void* d_out, int out_size, void* d_ws, size_t ws_size,
                              hipStream_t stream) {
    (void)in_sizes; (void)n_in; (void)out_size; (void)ws_size;
    const float* x  = (const float*)d_in[0];
    const float* Wq = (const float*)d_in[1];
    const float* bq = (const float*)d_in[2];
    const float* Wk = (const float*)d_in[3];
    const float* bk = (const float*)d_in[4];  (void)bk;  // cancels in softmax
    const float* Wv = (const float*)d_in[5];
    const float* bv = (const float*)d_in[6];
    const float* Ww = (const float*)d_in[7];
    const float* bw = (const float*)d_in[8];
    float* out = (float*)d_out;

    u16* xbf = (u16*)d_ws;                     // 4194304 u16 (8 MB)
    u16* Tbf = xbf + 4194304;                  // 4194304 u16 (8 MB)
    u16* aTb = Tbf + 4194304;                  // 65536 u16
    u16* wqb = aTb + 65536;                    // 65536 u16
    u16* wkb = wqb + 65536;                    // 65536 u16
    float* wvw = (float*)(wkb + 65536);        // 256 f32
    float* kbv = wvw + 256;                    // 256 f32
    float2* uee = (float2*)(kbv + 256);        // 16384 float2
    float* pnum = (float*)(uee + 16384);       // NSPLIT*16384 f32
    float* pden = pnum + NSPLIT * BATCH * NB;  // NSPLIT*16384 f32

    hipLaunchKernelGGL(wprep_kernel, dim3(256), dim3(256), 0, stream,
                       Wq, Wk, Wv, Ww, bq, wqb, wkb, wvw, kbv);
    // aT[f][e] = (Wk[f,:]·Wq[e,:])/16
    hipLaunchKernelGGL(gemm_bt_kernel, dim3(2, 4), dim3(256), 0, stream,
                       wkb, wqb, aTb, 0.0625f);
    hipLaunchKernelGGL(cvtu_kernel, dim3(4096), dim3(256), 0, stream,
                       x, wvw, kbv, bv, Ww, xbf, uee);
    // T = xbf @ aT^T (aTb rows are B-operand rows)
    hipLaunchKernelGGL(gemm_bt_kernel, dim3(128, 4), dim3(256), 0, stream,
                       xbf, aTb, Tbf, 1.0f);
    hipLaunchKernelGGL(attn_kernel, dim3(8 * 8 * NSPLIT), dim3(256), 0, stream,
                       Tbf, xbf, uee, pnum, pden);
    hipLaunchKernelGGL(finalize_kernel, dim3(64), dim3(256), 0, stream,
                       pnum, pden, bw, out);
}